// Round 5
// baseline (30.691 us; speedup 1.0000x reference)
//
#include <hip/hip_runtime.h>
#include <stdint.h>

#define H 512
#define W 512
#define HW (H * W)
#define KT 81       // 9x9 taps per pixel
#define PAD 4
#define SEGW 64     // pixels per block (one row segment)
#define BANDW (SEGW + 2 * PAD)   // 72
#define XDW (3 * 9 * BANDW)      // 1944 dwords of x band

__device__ __forceinline__ int reflect_idx(int p) {
    // jnp.pad mode="reflect": pad (4) < 512, one fold suffices
    if (p < 0) p = -p;
    if (p >= H) p = 2 * H - 2 - p;
    return p;
}

// 192 threads = 3 waves; wave c computes channel c of a 64-pixel row segment.
// BOTH weights and the x band live in LDS; per-lane reads are adjacent-dword
// pairs that the DS-combiner fuses into ds_read2_b32 (no alignment constraint).
// Weight banks: (17*l + t) mod 32 = permutation -> conflict-free.
// x banks: stride-1 -> 2 lanes/bank -> free.
__global__ __launch_bounds__(192) void svblur_kernel(
    const float* __restrict__ x,
    const float* __restrict__ kf,
    float* __restrict__ out)
{
    __shared__ float wlds[SEGW * KT];        // 20736 B
    __shared__ float xlds[3][9][BANDW];      // 7776 B  (total 28512 -> 5 blk/CU)

    const int tid = (int)threadIdx.x;
    const int l   = tid & 63;           // lane = pixel in segment
    const int wv  = tid >> 6;           // wave id = channel (0..2)
    const int bid = (int)blockIdx.x;
    const int h   = bid >> 3;           // 512 rows
    const int w0  = (bid & 7) << 6;     // 8 segments of 64 px per row

    // ---- Stage weights: 5184 contiguous dwords = 1296 float4 (21 wave-ops).
    {
        const float4* ws = (const float4*)(kf + ((size_t)h * W + w0) * KT);
        float4* wd = (float4*)wlds;
#pragma unroll
        for (int it = 0; it < 7; ++it) {
            int idx = (wv * 7 + it) * 64 + l;
            if (idx < (SEGW * KT) / 4)
                wd[idx] = ws[idx];
        }
    }

    // ---- Stage x band: 3 ch x 9 rows x 72 cols, reflect applied at load.
    // 1944 dwords over 192 threads -> ~30 coalesced wave-ops.
    {
#pragma unroll
        for (int it = 0; it < 11; ++it) {
            int idx = it * 192 + tid;
            if (idx < XDW) {
                int c   = idx / (9 * BANDW);
                int rem = idx - c * (9 * BANDW);
                int r   = rem / BANDW;
                int col = rem - r * BANDW;
                int gh = reflect_idx(h - PAD + r);
                int gw = reflect_idx(w0 - PAD + col);
                (&xlds[0][0][0])[idx] = x[(size_t)c * HW + gh * W + gw];
            }
        }
    }
    __syncthreads();

    // ---- Compute: all reads from LDS, paired into ds_read2_b32.
    const float* wp = wlds + l * KT;
    float acc = 0.f;
#pragma unroll
    for (int i = 0; i < 9; ++i) {
        const float* xr = &xlds[wv][i][l];
        float xv[9], wt[9];
#pragma unroll
        for (int j = 0; j < 9; ++j) xv[j] = xr[j];
#pragma unroll
        for (int j = 0; j < 9; ++j) wt[j] = wp[i * 9 + j];
#pragma unroll
        for (int j = 0; j < 9; ++j) acc = fmaf(xv[j], wt[j], acc);
    }

    out[(size_t)wv * HW + h * W + w0 + l] = acc;
}

extern "C" void kernel_launch(void* const* d_in, const int* in_sizes, int n_in,
                              void* d_out, int out_size, void* d_ws, size_t ws_size,
                              hipStream_t stream) {
    const float* x  = (const float*)d_in[0];
    const float* kf = (const float*)d_in[1];
    float* out = (float*)d_out;

    dim3 block(192);
    dim3 grid(H * (W / SEGW));   // 4096 blocks x 3 waves
    svblur_kernel<<<grid, block, 0, stream>>>(x, kf, out);
}

// Round 6
// 25.526 us; speedup vs baseline: 1.2023x; 1.2023x over previous
//
#include <hip/hip_runtime.h>
#include <stdint.h>

#define H 512
#define W 512
#define HW (H * W)
#define KT 81     // 9x9 taps per pixel
#define PAD 4
#define SEGW 64   // pixels per block (one row segment)

__device__ __forceinline__ int reflect_idx(int p) {
    // jnp.pad mode="reflect": pad (4) < 512, one fold suffices
    if (p < 0) p = -p;
    if (p >= H) p = 2 * H - 2 - p;
    return p;
}

// 192 threads = 3 waves; wave c computes channel c of a 64-pixel row segment.
// Weights staged coalesced -> LDS, read back per-lane at dword stride 81
// (bank = (17*l + t) mod 32 = permutation -> conflict-free, paired into
// ds_read2_b32 by the compiler).
// KEY CHANGE vs R4: all 81 x loads are issued into registers BEFORE any use
// (one vmcnt wait per wave instead of 27 exposed ~300cy round-trips), with
// zero per-load address VALU (uniform row base + 9 precomputed voffsets).
__global__ __launch_bounds__(192) void svblur_kernel(
    const float* __restrict__ x,
    const float* __restrict__ kf,
    float* __restrict__ out)
{
    __shared__ float wlds[SEGW * KT];   // 20736 B -> 7 blocks/CU (21 waves)

    const int tid = (int)threadIdx.x;
    const int l   = tid & 63;           // lane = pixel in segment
    const int wv  = tid >> 6;           // wave id = channel (0..2)
    const int bid = (int)blockIdx.x;
    const int h   = bid >> 3;           // 512 rows
    const int w0  = (bid & 7) << 6;     // 8 segments of 64 px per row

    // ---- Stage weights: 5184 contiguous dwords = 1296 float4, 7 ops/wave.
    {
        const float4* ws = (const float4*)(kf + ((size_t)h * W + w0) * KT);
        float4* wd = (float4*)wlds;
#pragma unroll
        for (int it = 0; it < 7; ++it) {
            int idx = (wv * 7 + it) * 64 + l;
            if (idx < (SEGW * KT) / 4)
                wd[idx] = ws[idx];
        }
    }
    __syncthreads();

    // Reflected column offsets, computed once; every x load is then
    // global_load_dword v, voff, s[rowbase] with no per-load VALU.
    int rgw[9];
#pragma unroll
    for (int j = 0; j < 9; ++j)
        rgw[j] = reflect_idx(w0 - PAD + l + j);

    const float* xc = x + (size_t)wv * HW;   // this wave's channel plane

    // ---- Issue ALL 81 x loads into registers (maximum MLP, one drain).
    float xv[81];
#pragma unroll
    for (int i = 0; i < 9; ++i) {
        const float* row = xc + (size_t)reflect_idx(h - PAD + i) * W;
#pragma unroll
        for (int j = 0; j < 9; ++j)
            xv[i * 9 + j] = row[rgw[j]];
    }

    // ---- FMA tail: LDS weight reads (paired) + 3 independent acc chains.
    const float* wp = wlds + l * KT;
    float a0 = 0.f, a1 = 0.f, a2 = 0.f;
#pragma unroll
    for (int t = 0; t < 81; t += 3) {
        a0 = fmaf(xv[t],     wp[t],     a0);
        if (t + 1 < 81) a1 = fmaf(xv[t + 1], wp[t + 1], a1);
        if (t + 2 < 81) a2 = fmaf(xv[t + 2], wp[t + 2], a2);
    }

    out[(size_t)wv * HW + h * W + w0 + l] = a0 + a1 + a2;
}

extern "C" void kernel_launch(void* const* d_in, const int* in_sizes, int n_in,
                              void* d_out, int out_size, void* d_ws, size_t ws_size,
                              hipStream_t stream) {
    const float* x  = (const float*)d_in[0];
    const float* kf = (const float*)d_in[1];
    float* out = (float*)d_out;

    dim3 block(192);
    dim3 grid(H * (W / SEGW));   // 4096 blocks x 3 waves
    svblur_kernel<<<grid, block, 0, stream>>>(x, kf, out);
}